// Round 2
// baseline (195.389 us; speedup 1.0000x reference)
//
#include <hip/hip_runtime.h>
#include <hip/hip_bf16.h>

#define N 8192
#define FIN 256
#define FOUT 128
#define ALPHA 0.2f

typedef unsigned short ushort_t;
typedef __attribute__((ext_vector_type(8))) short short8;
typedef __attribute__((ext_vector_type(4))) float f32x4;

__device__ __forceinline__ ushort_t f2bf(float x) {
  __hip_bfloat16 b = __float2bfloat16(x);  // RNE; compiler emits good code (m240)
  return *reinterpret_cast<ushort_t*>(&b);
}

// ---------------- Kernel 1: h = X@W (fp32), s1 = h@a1, s2 = h@a2, hT = bf16(h)^T ----
__global__ __launch_bounds__(256) void k_h(const float* __restrict__ inp,
                                           const float* __restrict__ Wm,
                                           const float* __restrict__ av,
                                           ushort_t* __restrict__ hT,
                                           float* __restrict__ s1,
                                           float* __restrict__ s2) {
  __shared__ float in_lds[16][FIN];    // 16 KB
  __shared__ float h_tile[16][FOUT];   // 8 KB
  const int t = threadIdx.x;
  const int r0 = blockIdx.x * 16;

  for (int idx = t; idx < 16 * FIN; idx += 256) {
    int ii = idx >> 8, kk = idx & 255;
    in_lds[ii][kk] = inp[(size_t)(r0 + ii) * FIN + kk];
  }
  __syncthreads();

  const int c2 = (t & 63) * 2;  // column pair
  const int rg = t >> 6;        // row group: rows rg*4 .. rg*4+3
  float acc[4][2] = {};
  for (int k = 0; k < FIN; k += 4) {
    float4 iv[4];
#pragma unroll
    for (int q = 0; q < 4; ++q)
      iv[q] = *reinterpret_cast<const float4*>(&in_lds[rg * 4 + q][k]);
#pragma unroll
    for (int kk = 0; kk < 4; ++kk) {
      float2 wp = *reinterpret_cast<const float2*>(&Wm[(size_t)(k + kk) * FOUT + c2]);
#pragma unroll
      for (int q = 0; q < 4; ++q) {
        float x = reinterpret_cast<const float*>(&iv[q])[kk];
        acc[q][0] = fmaf(x, wp.x, acc[q][0]);
        acc[q][1] = fmaf(x, wp.y, acc[q][1]);
      }
    }
  }
#pragma unroll
  for (int q = 0; q < 4; ++q) {
    h_tile[rg * 4 + q][c2] = acc[q][0];
    h_tile[rg * 4 + q][c2 + 1] = acc[q][1];
  }
  __syncthreads();

  // s1/s2: wave w reduces rows 4w..4w+3 over 128 cols
  const int wv_ = t >> 6, lane = t & 63;
#pragma unroll
  for (int rr = 0; rr < 4; ++rr) {
    int row = wv_ * 4 + rr;
    float h0 = h_tile[row][lane], h1 = h_tile[row][lane + 64];
    float p1 = h0 * av[lane] + h1 * av[lane + 64];
    float p2 = h0 * av[FOUT + lane] + h1 * av[FOUT + lane + 64];
#pragma unroll
    for (int m = 32; m; m >>= 1) {
      p1 += __shfl_xor(p1, m);
      p2 += __shfl_xor(p2, m);
    }
    if (lane == 0) { s1[r0 + row] = p1; s2[r0 + row] = p2; }
  }

  // hT[c][r] = bf16(h[r][c])
  for (int idx = t; idx < 16 * FOUT; idx += 256) {
    int c = idx >> 4, ii = idx & 15;
    hT[(size_t)c * N + r0 + ii] = f2bf(h_tile[ii][c]);
  }
}

// ---------------- Kernel 1b: global max of s2 -------------------------------------
__global__ __launch_bounds__(256) void k_smax(const float* __restrict__ s2,
                                              float* __restrict__ outm) {
  __shared__ float red[4];
  const int t = threadIdx.x;
  float m = -1e30f;
  for (int i = t; i < N; i += 256) m = fmaxf(m, s2[i]);
#pragma unroll
  for (int d = 32; d; d >>= 1) m = fmaxf(m, __shfl_xor(m, d));
  if ((t & 63) == 0) red[t >> 6] = m;
  __syncthreads();
  if (t == 0) outm[0] = fmaxf(fmaxf(red[0], red[1]), fmaxf(red[2], red[3]));
}

// ---------------- Kernel 2: masked softmax + P@h (MFMA), barrier-free main loop ---
// 512 blocks x 512 threads (8 waves). Block owns 16 rows x 128 cols of output.
// Wave w owns k-slice j%256 in [32w, 32w+32): computes its A-fragment weights
// IN REGISTER (lane l: row l&15, j-offset (l>>4)*8+e) and accumulates a k-partial
// of the full 16x128 output tile via 8 MFMAs per 256-j tile. No LDS, no barriers
// until the one-time epilogue reduction.
__global__ __launch_bounds__(512, 4) void k_attn(const int* __restrict__ adj,
                                                 const ushort_t* __restrict__ hT,
                                                 const float* __restrict__ s1g,
                                                 const float* __restrict__ s2g,
                                                 const float* __restrict__ s2max,
                                                 float* __restrict__ out) {
  __shared__ float Hred[16][132];  // padded: +4 breaks 128-stride -> <=2-way conflict
  __shared__ float Dred[8][16];

  const int t = threadIdx.x;
  const int lane = t & 63;
  const int wid = t >> 6;
  const int i0 = blockIdx.x * 16;
  const int row = lane & 15;   // A-frag row == adj row; also B-frag col
  const int kb = lane >> 4;    // k-subblock 0..3

  const float s1v = s1g[i0 + row];
  const float mraw = s1v + s2max[0];
  const float mv = mraw > 0.f ? mraw : ALPHA * mraw;  // m~_i >= max_j e_ij (monotone)
  const float L2E = 1.44269504f;
  const float mvl = mv * L2E;

  const int jw = wid * 32 + kb * 8;  // lane's base j within each 256-tile
  const int* __restrict__ adjp = adj + (size_t)(i0 + row) * N + jw;
  const float* __restrict__ s2p = s2g + jw;
  const ushort_t* __restrict__ bp = hT + (size_t)row * N + jw;  // + ct*16*N + it*256

  f32x4 acc[8];
#pragma unroll
  for (int ct = 0; ct < 8; ++ct) acc[ct] = (f32x4){0.f, 0.f, 0.f, 0.f};
  float dacc = 0.f;

#define COMPUTE(C0, C1, G0, G1, J0)                                         \
  {                                                                         \
    const int* ai = reinterpret_cast<const int*>(&(C0));                    \
    const int* ai2 = reinterpret_cast<const int*>(&(C1));                   \
    const float* sf = reinterpret_cast<const float*>(&(G0));                \
    const float* sf2 = reinterpret_cast<const float*>(&(G1));               \
    short8 af;                                                              \
    _Pragma("unroll") for (int e = 0; e < 4; ++e) {                         \
      float pre = s1v + sf[e];                                              \
      float lr = fmaxf(pre, ALPHA * pre);                                   \
      float w = __builtin_amdgcn_exp2f(fmaf(lr, L2E, -mvl));                \
      w = (ai[e] > 0) ? w : 0.f;                                            \
      dacc += w;                                                            \
      af[e] = (short)f2bf(w);                                               \
    }                                                                       \
    _Pragma("unroll") for (int e = 0; e < 4; ++e) {                         \
      float pre = s1v + sf2[e];                                             \
      float lr = fmaxf(pre, ALPHA * pre);                                   \
      float w = __builtin_amdgcn_exp2f(fmaf(lr, L2E, -mvl));                \
      w = (ai2[e] > 0) ? w : 0.f;                                           \
      dacc += w;                                                            \
      af[4 + e] = (short)f2bf(w);                                           \
    }                                                                       \
    const ushort_t* bb = bp + (J0);                                         \
    short8 bf[8];                                                           \
    _Pragma("unroll") for (int ct = 0; ct < 8; ++ct)                        \
      bf[ct] = *reinterpret_cast<const short8*>(bb + (size_t)ct * 16 * N);  \
    _Pragma("unroll") for (int ct = 0; ct < 8; ++ct)                        \
      acc[ct] = __builtin_amdgcn_mfma_f32_16x16x32_bf16(af, bf[ct], acc[ct], 0, 0, 0); \
  }

  // 2-deep software prefetch of the adj (HBM) + s2 streams; slots A/B, no arrays
  // with runtime index (rule #20).
  int4 aA0 = *reinterpret_cast<const int4*>(adjp);
  int4 aA1 = *reinterpret_cast<const int4*>(adjp + 4);
  float4 sA0 = *reinterpret_cast<const float4*>(s2p);
  float4 sA1 = *reinterpret_cast<const float4*>(s2p + 4);
  int4 aB0 = *reinterpret_cast<const int4*>(adjp + 256);
  int4 aB1 = *reinterpret_cast<const int4*>(adjp + 260);
  float4 sB0 = *reinterpret_cast<const float4*>(s2p + 256);
  float4 sB1 = *reinterpret_cast<const float4*>(s2p + 260);

  for (int it = 0; it < 32; it += 2) {
    {
      int4 c0 = aA0, c1 = aA1;
      float4 g0 = sA0, g1 = sA1;
      if (it + 2 < 32) {
        aA0 = *reinterpret_cast<const int4*>(adjp + (it + 2) * 256);
        aA1 = *reinterpret_cast<const int4*>(adjp + (it + 2) * 256 + 4);
        sA0 = *reinterpret_cast<const float4*>(s2p + (it + 2) * 256);
        sA1 = *reinterpret_cast<const float4*>(s2p + (it + 2) * 256 + 4);
      }
      COMPUTE(c0, c1, g0, g1, it * 256)
    }
    {
      int4 c0 = aB0, c1 = aB1;
      float4 g0 = sB0, g1 = sB1;
      if (it + 3 < 32) {
        aB0 = *reinterpret_cast<const int4*>(adjp + (it + 3) * 256);
        aB1 = *reinterpret_cast<const int4*>(adjp + (it + 3) * 256 + 4);
        sB0 = *reinterpret_cast<const float4*>(s2p + (it + 3) * 256);
        sB1 = *reinterpret_cast<const float4*>(s2p + (it + 3) * 256 + 4);
      }
      COMPUTE(c0, c1, g0, g1, (it + 1) * 256)
    }
  }
#undef COMPUTE

  // ---- denominator: lanes {r, r+16, r+32, r+48} share row r ----
  dacc += __shfl_xor(dacc, 16);
  dacc += __shfl_xor(dacc, 32);
  if (lane < 16) Dred[wid][lane] = dacc;

  // ---- cross-wave reduction of the k-partial 16x128 tiles (one-time) ----
  // C/D layout (m89-verified): col = ct*16 + (lane&15), row = (lane>>4)*4 + r
  for (int wv = 0; wv < 8; ++wv) {
    if (wid == wv) {
#pragma unroll
      for (int ct = 0; ct < 8; ++ct)
#pragma unroll
        for (int r = 0; r < 4; ++r) {
          int orow = kb * 4 + r;
          int ocol = ct * 16 + row;
          if (wv == 0)
            Hred[orow][ocol] = acc[ct][r];
          else
            Hred[orow][ocol] += acc[ct][r];
        }
    }
    __syncthreads();
  }

  // ---- epilogue: divide by denom, ELU, store ----
  for (int idx = t; idx < 16 * FOUT; idx += 512) {
    int orow = idx >> 7, ocol = idx & 127;
    float den = 0.f;
#pragma unroll
    for (int wv = 0; wv < 8; ++wv) den += Dred[wv][orow];
    float v = Hred[orow][ocol] / den;
    out[(size_t)(i0 + orow) * FOUT + ocol] = v > 0.f ? v : (__expf(v) - 1.f);
  }
}

extern "C" void kernel_launch(void* const* d_in, const int* in_sizes, int n_in,
                              void* d_out, int out_size, void* d_ws, size_t ws_size,
                              hipStream_t stream) {
  const float* inp = (const float*)d_in[0];   // [N][FIN] fp32
  const int* adj   = (const int*)d_in[1];     // [N][N] int32
  const float* Wm  = (const float*)d_in[2];   // [FIN][FOUT] fp32
  const float* av  = (const float*)d_in[3];   // [2*FOUT] fp32
  float* out = (float*)d_out;

  // workspace carve-up
  char* ws = (char*)d_ws;
  ushort_t* hT = (ushort_t*)ws;                              // 128*8192*2 = 2 MB
  float* s1    = (float*)(ws + (size_t)FOUT * N * 2);        // 32 KB
  float* s2    = s1 + N;                                     // 32 KB
  float* s2mx  = s2 + N;                                     // 4 B

  k_h<<<N / 16, 256, 0, stream>>>(inp, Wm, av, hT, s1, s2);
  k_smax<<<1, 256, 0, stream>>>(s2, s2mx);
  k_attn<<<N / 16, 512, 0, stream>>>(adj, hT, s1, s2, s2mx, out);
}